// Round 6
// baseline (418.398 us; speedup 1.0000x reference)
//
#include <hip/hip_runtime.h>
#include <hip/hip_bf16.h>
#include <cstdint>

using bf16 = __hip_bfloat16;
typedef __attribute__((ext_vector_type(8))) short bf16x8;
typedef __attribute__((ext_vector_type(4))) float f32x4;

// problem constants: DIM=1024, HEADS=16, HD=64, B=2, S=2048
// workspace layout (bf16 element offsets); total 24M elems = 48 MB
constexpr size_t OFF_WQT = 0;                 // 1M each, transposed bf16 weights
constexpr size_t OFF_WKT = (size_t)1 << 20;
constexpr size_t OFF_WVT = (size_t)2 << 20;
constexpr size_t OFF_WOT = (size_t)3 << 20;
constexpr size_t OFF_HB  = (size_t)4 << 20;  // H as bf16 [4096][1024]
constexpr size_t OFF_Q   = (size_t)8 << 20;  // [b*16+h][s][d]
constexpr size_t OFF_K   = (size_t)12 << 20; // [b*16+h][s][d]
constexpr size_t OFF_VT  = (size_t)16 << 20; // [b*16+h][d][s]
constexpr size_t OFF_ATT = (size_t)20 << 20; // [b*2048+s][h*64+d]

__device__ __forceinline__ void gload_lds16(const void* g, void* l) {
  auto gp = reinterpret_cast<const __attribute__((address_space(1))) void*>(
      reinterpret_cast<uintptr_t>(g));
  auto lp = reinterpret_cast<__attribute__((address_space(3))) void*>(
      static_cast<uint32_t>(reinterpret_cast<uintptr_t>(l)));
  __builtin_amdgcn_global_load_lds(gp, lp, 16, 0, 0);
}

__device__ __forceinline__ short f2b(float x) {
  return (short)__builtin_bit_cast(unsigned short, __float2bfloat16(x));
}

// ---------------- H: f32 -> bf16, 8 elems/thread ----------------
__global__ __launch_bounds__(256) void cvt_h(const float* __restrict__ in,
                                             bf16* __restrict__ out) {
  const int i = blockIdx.x * 256 + threadIdx.x;  // 4M/8 = 512K threads
  const f32x4 a = *(const f32x4*)(in + (size_t)i * 8);
  const f32x4 b = *(const f32x4*)(in + (size_t)i * 8 + 4);
  bf16x8 v;
  v[0] = f2b(a[0]); v[1] = f2b(a[1]); v[2] = f2b(a[2]); v[3] = f2b(a[3]);
  v[4] = f2b(b[0]); v[5] = f2b(b[1]); v[6] = f2b(b[2]); v[7] = f2b(b[3]);
  *(bf16x8*)((short*)out + (size_t)i * 8) = v;
}

// ---------------- weight transpose + cvt: WT[n][k] = bf16(W[k][n]) ----------------
__global__ __launch_bounds__(256) void transpose_w(
    const float* __restrict__ w0, const float* __restrict__ w1,
    const float* __restrict__ w2, const float* __restrict__ w3,
    bf16* __restrict__ ws) {
  __shared__ float t[64][65];
  const float* src = (blockIdx.z == 0) ? w0 : (blockIdx.z == 1) ? w1
                   : (blockIdx.z == 2) ? w2 : w3;
  bf16* dst = ws + ((size_t)blockIdx.z << 20);
  const int r0 = blockIdx.y * 64, c0 = blockIdx.x * 64;
  for (int i = threadIdx.x; i < 4096; i += 256) {
    const int r = i >> 6, c = i & 63;
    t[r][c] = src[(size_t)(r0 + r) * 1024 + c0 + c];
  }
  __syncthreads();
  for (int i = threadIdx.x; i < 4096; i += 256) {
    const int r = i >> 6, c = i & 63;
    dst[(size_t)(c0 + r) * 1024 + r0 + c] = __float2bfloat16(t[c][r]);
  }
}

// ---------------- GEMM: C = A(MxK) * Bt(NxK)^T, K=1024, tiles 128x128x64 ----------------
// MODE 0: A=Hb, Bt=WqT/WkT (z), C-> q/k ws [bh][s][d] (bf16), Q scaled by 0.125
// MODE 1: A=WvT (M=1024), Bt=Hb (N=4096), C-> vt ws [bh][d][s] (bf16)
// MODE 2: A=att, Bt=WoT, C-> d_out [m][n] (FLOAT32 - reference output dtype)
template <int MODE>
__global__ __launch_bounds__(256) void gemm_k(
    const bf16* __restrict__ A, const bf16* __restrict__ Bt0,
    const bf16* __restrict__ Bt1, void* __restrict__ C0, void* __restrict__ C1) {
  __shared__ __attribute__((aligned(16))) bf16 As[128 * 64];
  __shared__ __attribute__((aligned(16))) bf16 Bs[128 * 64];
  const int tid = threadIdx.x;
  const int wv = tid >> 6, ln = tid & 63;
  const int m0 = blockIdx.y * 128, n0 = blockIdx.x * 128;
  const bf16* Bt = (MODE == 0 && blockIdx.z == 1) ? Bt1 : Bt0;
  void* C = (MODE == 0 && blockIdx.z == 1) ? C1 : C0;
  const int wm = (wv >> 1) * 64, wn = (wv & 1) * 64;
  const int srow = ln >> 3, scol = (ln & 7) * 8;
  f32x4 acc[4][4] = {};

  for (int kt = 0; kt < 16; ++kt) {
    __syncthreads();  // previous tile fully consumed
    const int kb = kt * 64;
#pragma unroll
    for (int j = 0; j < 4; ++j) {
      const int rr = (wv * 4 + j) * 8 + srow;
      gload_lds16(A  + (size_t)(m0 + rr) * 1024 + kb + scol, As + (size_t)(wv * 4 + j) * 512);
      gload_lds16(Bt + (size_t)(n0 + rr) * 1024 + kb + scol, Bs + (size_t)(wv * 4 + j) * 512);
    }
    __syncthreads();  // compiler drains vmcnt(0) before barrier
#pragma unroll
    for (int ks = 0; ks < 2; ++ks) {
      bf16x8 af[4], bfr[4];
#pragma unroll
      for (int i = 0; i < 4; ++i) {
        af[i]  = *(const bf16x8*)(As + (wm + i * 16 + (ln & 15)) * 64 + ks * 32 + (ln >> 4) * 8);
        bfr[i] = *(const bf16x8*)(Bs + (wn + i * 16 + (ln & 15)) * 64 + ks * 32 + (ln >> 4) * 8);
      }
#pragma unroll
      for (int i = 0; i < 4; ++i)
#pragma unroll
        for (int j = 0; j < 4; ++j)
          acc[i][j] = __builtin_amdgcn_mfma_f32_16x16x32_bf16(af[i], bfr[j], acc[i][j], 0, 0, 0);
    }
  }

  const float scl = (MODE == 0 && blockIdx.z == 0) ? 0.125f : 1.0f;
#pragma unroll
  for (int i = 0; i < 4; ++i)
#pragma unroll
    for (int j = 0; j < 4; ++j)
#pragma unroll
      for (int r = 0; r < 4; ++r) {
        const int m = m0 + wm + i * 16 + (ln >> 4) * 4 + r;
        const int n = n0 + wn + j * 16 + (ln & 15);
        const float v = acc[i][j][r] * scl;
        if (MODE == 0) {
          // [b*16+h][s][d]: b=m>>11, s=m&2047, h=n>>6, d=n&63
          const size_t idx =
              ((size_t)((m >> 11) * 16 + (n >> 6)) << 17) + (size_t)(m & 2047) * 64 + (n & 63);
          ((bf16*)C)[idx] = __float2bfloat16(v);
        } else if (MODE == 1) {
          // C[m][n] = V^T value, m = h*64+d, n = b*2048+s -> vt[b][m][s]
          const size_t idx = ((size_t)(n >> 11) << 21) + (size_t)m * 2048 + (n & 2047);
          ((bf16*)C)[idx] = __float2bfloat16(v);
        } else {
          // final output: reference dtype is float32
          ((float*)C)[(size_t)m * 1024 + n] = v;
        }
      }
}

// ---------------- attention: per (b,h), 128 q-rows per block ----------------
// 8 waves: quad 0 (waves 0-3) handles kv [0,1024), quad 1 (waves 4-7) kv [1024,2048).
// No max-subtraction -> partials merge by pure addition (O=O0+O1, l=l0+l1).
__global__ __launch_bounds__(512, 4) void attn_k(
    const bf16* __restrict__ qg, const bf16* __restrict__ kg,
    const bf16* __restrict__ vtg, const int* __restrict__ mask,
    bf16* __restrict__ att) {
  __shared__ __attribute__((aligned(16))) short Ps[256 * 64];  // 8 per-wave 32-row stripes
  __shared__ float Ob[4][32][65];  // quad-1 partial O (stride 65 kills bank conflicts)
  __shared__ float Lb[4][32];      // quad-1 partial denominators
  const int tid = threadIdx.x, wv = tid >> 6, ln = tid & 63;
  const int quad = wv >> 2, wq = wv & 3;
  const int bh = blockIdx.y, b = bh >> 4, h = bh & 15;
  const int q0 = blockIdx.x * 128;
  const bf16* qh  = qg  + (size_t)bh * (2048 * 64);
  const bf16* kh  = kg  + (size_t)bh * (2048 * 64);
  const bf16* vth = vtg + (size_t)bh * (64 * 2048);
  const int* mb = mask + b * 2048;
  const int g = ln >> 4, c = ln & 15;

  // hoist Q fragments (A-layout: row=c, k-chunk=g); q-rows owned by wq
  bf16x8 qf[2][2];
#pragma unroll
  for (int mr = 0; mr < 2; ++mr)
#pragma unroll
    for (int ks = 0; ks < 2; ++ks)
      qf[mr][ks] = *(const bf16x8*)(qh + (size_t)(q0 + wq * 32 + mr * 16 + c) * 64 + ks * 32 + g * 8);

  // constant ones B-fragment: column 0 = 1 -> row-sum of P via MFMA
  bf16x8 onesf;
#pragma unroll
  for (int i = 0; i < 8; ++i) onesf[i] = (c == 0) ? (short)0x3F80 : (short)0;

  f32x4 o[2][4] = {};
  f32x4 ol[2] = {};

  for (int t = 0; t < 16; ++t) {
    const int kt = quad * 16 + t;
    // ---- scores = Q K^T (K frags direct from global; L2-resident) ----
    f32x4 sf[2][4] = {};
#pragma unroll
    for (int ks = 0; ks < 2; ++ks) {
      bf16x8 kf[4];
#pragma unroll
      for (int nk = 0; nk < 4; ++nk)
        kf[nk] = *(const bf16x8*)(kh + (size_t)(kt * 64 + nk * 16 + c) * 64 + ks * 32 + g * 8);
#pragma unroll
      for (int mr = 0; mr < 2; ++mr)
#pragma unroll
        for (int nk = 0; nk < 4; ++nk)
          sf[mr][nk] = __builtin_amdgcn_mfma_f32_16x16x32_bf16(qf[mr][ks], kf[nk], sf[mr][nk], 0, 0, 0);
    }
    // ---- P = exp(min(s,30)), masked -> 0; bounce via wave-private swizzled LDS stripe ----
#pragma unroll
    for (int nk = 0; nk < 4; ++nk) {
      const bool live = (mb[kt * 64 + nk * 16 + c] != 0);
#pragma unroll
      for (int mr = 0; mr < 2; ++mr)
#pragma unroll
        for (int r = 0; r < 4; ++r) {
          const float p = live ? __expf(fminf(sf[mr][nk][r], 30.0f)) : 0.0f;
          const int qr = wv * 32 + mr * 16 + g * 4 + r;
          *(short*)((char*)Ps + qr * 128 + (((nk * 16 + c) * 2) ^ ((qr & 7) << 4))) = f2b(p);
        }
    }
    asm volatile("" ::: "memory");  // order P-writes before P-reads
    // ---- O += P V ; denominator accumulated as ones-column MFMA ----
#pragma unroll
    for (int ks = 0; ks < 2; ++ks) {
      bf16x8 pf[2], vf[4];
#pragma unroll
      for (int mr = 0; mr < 2; ++mr) {
        const int qr = wv * 32 + mr * 16 + c;
        pf[mr] = *(const bf16x8*)((const char*)Ps + qr * 128 + ((ks * 64 + g * 16) ^ ((qr & 7) << 4)));
      }
#pragma unroll
      for (int nd = 0; nd < 4; ++nd)
        vf[nd] = *(const bf16x8*)(vth + (size_t)(nd * 16 + c) * 2048 + kt * 64 + ks * 32 + g * 8);
#pragma unroll
      for (int mr = 0; mr < 2; ++mr) {
#pragma unroll
        for (int nd = 0; nd < 4; ++nd)
          o[mr][nd] = __builtin_amdgcn_mfma_f32_16x16x32_bf16(pf[mr], vf[nd], o[mr][nd], 0, 0, 0);
        ol[mr] = __builtin_amdgcn_mfma_f32_16x16x32_bf16(pf[mr], onesf, ol[mr], 0, 0, 0);
      }
    }
    asm volatile("" ::: "memory");  // order P-reads before next tile's P-writes
  }

  // ---- merge quads: quad 1 stores partials, quad 0 adds, normalizes, writes ----
  if (quad == 1) {
#pragma unroll
    for (int mr = 0; mr < 2; ++mr) {
#pragma unroll
      for (int nd = 0; nd < 4; ++nd)
#pragma unroll
        for (int r = 0; r < 4; ++r)
          Ob[wq][mr * 16 + g * 4 + r][nd * 16 + c] = o[mr][nd][r];
      if (c == 0)
#pragma unroll
        for (int r = 0; r < 4; ++r) Lb[wq][mr * 16 + g * 4 + r] = ol[mr][r];
    }
  }
  __syncthreads();
  if (quad == 0) {
#pragma unroll
    for (int mr = 0; mr < 2; ++mr)
#pragma unroll
      for (int r = 0; r < 4; ++r) {
        const int row = mr * 16 + g * 4 + r;
        const float lsum = __shfl(ol[mr][r], ln & 48, 64) + Lb[wq][row];
        const float inv = 1.0f / fmaxf(lsum, 1e-30f);
        const int qr = q0 + wq * 32 + row;
#pragma unroll
        for (int nd = 0; nd < 4; ++nd)
          att[(size_t)(b * 2048 + qr) * 1024 + h * 64 + nd * 16 + c] =
              __float2bfloat16((o[mr][nd][r] + Ob[wq][row][nd * 16 + c]) * inv);
      }
  }
}

extern "C" void kernel_launch(void* const* d_in, const int* in_sizes, int n_in,
                              void* d_out, int out_size, void* d_ws, size_t ws_size,
                              hipStream_t stream) {
  (void)in_sizes; (void)n_in; (void)out_size; (void)ws_size;
  const float* H    = (const float*)d_in[0];   // inputs are float32 per reference
  const int*   mask = (const int*)d_in[1];
  const float* Wq   = (const float*)d_in[2];
  const float* Wk   = (const float*)d_in[3];
  const float* Wv   = (const float*)d_in[4];
  const float* Wo   = (const float*)d_in[5];
  bf16* ws   = (bf16*)d_ws;
  bf16* wqT  = ws + OFF_WQT;
  bf16* wkT  = ws + OFF_WKT;
  bf16* wvT  = ws + OFF_WVT;
  bf16* woT  = ws + OFF_WOT;
  bf16* hb   = ws + OFF_HB;
  bf16* qws  = ws + OFF_Q;
  bf16* kws  = ws + OFF_K;
  bf16* vtws = ws + OFF_VT;
  bf16* attw = ws + OFF_ATT;

  transpose_w<<<dim3(16, 16, 4), 256, 0, stream>>>(Wq, Wk, Wv, Wo, ws);
  cvt_h<<<dim3(2048), 256, 0, stream>>>(H, hb);   // 4M elems, 8/thread
  // Q and K projections (z=0 -> Q scaled, z=1 -> K)
  gemm_k<0><<<dim3(8, 32, 2), 256, 0, stream>>>(hb, wqT, wkT, qws, kws);
  // V^T = WvT @ Hb^T  (M=1024 -> grid.y=8, N=4096 -> grid.x=32)
  gemm_k<1><<<dim3(32, 8, 1), 256, 0, stream>>>(wvT, hb, nullptr, vtws, nullptr);
  // attention: 512 threads, kv-split across wave-quads
  attn_k<<<dim3(16, 32), 512, 0, stream>>>(qws, kws, vtws, mask, attw);
  // output projection -> float32 d_out
  gemm_k<2><<<dim3(8, 32, 1), 256, 0, stream>>>(attw, woT, nullptr, d_out, nullptr);
}

// Round 7
// 397.833 us; speedup vs baseline: 1.0517x; 1.0517x over previous
//
#include <hip/hip_runtime.h>
#include <hip/hip_bf16.h>
#include <cstdint>

using bf16 = __hip_bfloat16;
typedef __attribute__((ext_vector_type(8))) short bf16x8;
typedef __attribute__((ext_vector_type(4))) float f32x4;

// problem constants: DIM=1024, HEADS=16, HD=64, B=2, S=2048
// workspace layout (bf16 element offsets); total 24M elems = 48 MB
constexpr size_t OFF_WQT = 0;                 // 1M each, transposed bf16 weights
constexpr size_t OFF_WKT = (size_t)1 << 20;
constexpr size_t OFF_WVT = (size_t)2 << 20;
constexpr size_t OFF_WOT = (size_t)3 << 20;
constexpr size_t OFF_HB  = (size_t)4 << 20;  // H as bf16 [4096][1024]
constexpr size_t OFF_Q   = (size_t)8 << 20;  // [b*16+h][s][d]
constexpr size_t OFF_K   = (size_t)12 << 20; // [b*16+h][s][d]
constexpr size_t OFF_VT  = (size_t)16 << 20; // [b*16+h][d][s]
constexpr size_t OFF_ATT = (size_t)20 << 20; // [b*2048+s][h*64+d]

__device__ __forceinline__ void gload_lds16(const void* g, void* l) {
  auto gp = reinterpret_cast<const __attribute__((address_space(1))) void*>(
      reinterpret_cast<uintptr_t>(g));
  auto lp = reinterpret_cast<__attribute__((address_space(3))) void*>(
      static_cast<uint32_t>(reinterpret_cast<uintptr_t>(l)));
  __builtin_amdgcn_global_load_lds(gp, lp, 16, 0, 0);
}

__device__ __forceinline__ short f2b(float x) {
  return (short)__builtin_bit_cast(unsigned short, __float2bfloat16(x));
}

// ---------------- H: f32 -> bf16, 8 elems/thread ----------------
__global__ __launch_bounds__(256) void cvt_h(const float* __restrict__ in,
                                             bf16* __restrict__ out) {
  const int i = blockIdx.x * 256 + threadIdx.x;  // 4M/8 = 512K threads
  const f32x4 a = *(const f32x4*)(in + (size_t)i * 8);
  const f32x4 b = *(const f32x4*)(in + (size_t)i * 8 + 4);
  bf16x8 v;
  v[0] = f2b(a[0]); v[1] = f2b(a[1]); v[2] = f2b(a[2]); v[3] = f2b(a[3]);
  v[4] = f2b(b[0]); v[5] = f2b(b[1]); v[6] = f2b(b[2]); v[7] = f2b(b[3]);
  *(bf16x8*)((short*)out + (size_t)i * 8) = v;
}

// ---------------- weight transpose + cvt: WT[n][k] = bf16(W[k][n]) ----------------
__global__ __launch_bounds__(256) void transpose_w(
    const float* __restrict__ w0, const float* __restrict__ w1,
    const float* __restrict__ w2, const float* __restrict__ w3,
    bf16* __restrict__ ws) {
  __shared__ float t[64][65];
  const float* src = (blockIdx.z == 0) ? w0 : (blockIdx.z == 1) ? w1
                   : (blockIdx.z == 2) ? w2 : w3;
  bf16* dst = ws + ((size_t)blockIdx.z << 20);
  const int r0 = blockIdx.y * 64, c0 = blockIdx.x * 64;
  for (int i = threadIdx.x; i < 4096; i += 256) {
    const int r = i >> 6, c = i & 63;
    t[r][c] = src[(size_t)(r0 + r) * 1024 + c0 + c];
  }
  __syncthreads();
  for (int i = threadIdx.x; i < 4096; i += 256) {
    const int r = i >> 6, c = i & 63;
    dst[(size_t)(c0 + r) * 1024 + r0 + c] = __float2bfloat16(t[c][r]);
  }
}

// ---------------- GEMM: C = A(MxK) * Bt(NxK)^T, K=1024, tiles 128x128x64 ----------------
// MODE 0: A=Hb, Bt=WqT/WkT (z), C-> q/k ws [bh][s][d] (bf16), Q scaled by 0.125
// MODE 1: A=WvT (M=1024), Bt=Hb (N=4096), C-> vt ws [bh][d][s] (bf16)
// MODE 2: A=att, Bt=WoT, C-> d_out [m][n] (FLOAT32 - reference output dtype)
template <int MODE>
__global__ __launch_bounds__(256) void gemm_k(
    const bf16* __restrict__ A, const bf16* __restrict__ Bt0,
    const bf16* __restrict__ Bt1, void* __restrict__ C0, void* __restrict__ C1) {
  __shared__ __attribute__((aligned(16))) bf16 As[128 * 64];
  __shared__ __attribute__((aligned(16))) bf16 Bs[128 * 64];
  const int tid = threadIdx.x;
  const int wv = tid >> 6, ln = tid & 63;
  const int m0 = blockIdx.y * 128, n0 = blockIdx.x * 128;
  const bf16* Bt = (MODE == 0 && blockIdx.z == 1) ? Bt1 : Bt0;
  void* C = (MODE == 0 && blockIdx.z == 1) ? C1 : C0;
  const int wm = (wv >> 1) * 64, wn = (wv & 1) * 64;
  const int srow = ln >> 3, scol = (ln & 7) * 8;
  f32x4 acc[4][4] = {};

  for (int kt = 0; kt < 16; ++kt) {
    __syncthreads();  // previous tile fully consumed
    const int kb = kt * 64;
#pragma unroll
    for (int j = 0; j < 4; ++j) {
      const int rr = (wv * 4 + j) * 8 + srow;
      gload_lds16(A  + (size_t)(m0 + rr) * 1024 + kb + scol, As + (size_t)(wv * 4 + j) * 512);
      gload_lds16(Bt + (size_t)(n0 + rr) * 1024 + kb + scol, Bs + (size_t)(wv * 4 + j) * 512);
    }
    __syncthreads();  // compiler drains vmcnt(0) before barrier
#pragma unroll
    for (int ks = 0; ks < 2; ++ks) {
      bf16x8 af[4], bfr[4];
#pragma unroll
      for (int i = 0; i < 4; ++i) {
        af[i]  = *(const bf16x8*)(As + (wm + i * 16 + (ln & 15)) * 64 + ks * 32 + (ln >> 4) * 8);
        bfr[i] = *(const bf16x8*)(Bs + (wn + i * 16 + (ln & 15)) * 64 + ks * 32 + (ln >> 4) * 8);
      }
#pragma unroll
      for (int i = 0; i < 4; ++i)
#pragma unroll
        for (int j = 0; j < 4; ++j)
          acc[i][j] = __builtin_amdgcn_mfma_f32_16x16x32_bf16(af[i], bfr[j], acc[i][j], 0, 0, 0);
    }
  }

  const float scl = (MODE == 0 && blockIdx.z == 0) ? 0.125f : 1.0f;
#pragma unroll
  for (int i = 0; i < 4; ++i)
#pragma unroll
    for (int j = 0; j < 4; ++j)
#pragma unroll
      for (int r = 0; r < 4; ++r) {
        const int m = m0 + wm + i * 16 + (ln >> 4) * 4 + r;
        const int n = n0 + wn + j * 16 + (ln & 15);
        const float v = acc[i][j][r] * scl;
        if (MODE == 0) {
          // [b*16+h][s][d]: b=m>>11, s=m&2047, h=n>>6, d=n&63
          const size_t idx =
              ((size_t)((m >> 11) * 16 + (n >> 6)) << 17) + (size_t)(m & 2047) * 64 + (n & 63);
          ((bf16*)C)[idx] = __float2bfloat16(v);
        } else if (MODE == 1) {
          // C[m][n] = V^T value, m = h*64+d, n = b*2048+s -> vt[b][m][s]
          const size_t idx = ((size_t)(n >> 11) << 21) + (size_t)m * 2048 + (n & 2047);
          ((bf16*)C)[idx] = __float2bfloat16(v);
        } else {
          // final output: reference dtype is float32
          ((float*)C)[(size_t)m * 1024 + n] = v;
        }
      }
}

// ---------------- attention: per (b,h), 64 q-rows per block, 4 waves x 16 rows ----------------
// Grid 32x32 = 1024 blocks -> 4 blocks/CU -> 16 waves/CU (round-5 was grid-limited at 8).
__global__ __launch_bounds__(256) void attn_k(
    const bf16* __restrict__ qg, const bf16* __restrict__ kg,
    const bf16* __restrict__ vtg, const int* __restrict__ mask,
    bf16* __restrict__ att) {
  __shared__ __attribute__((aligned(16))) short Ps[64 * 64];  // 4 per-wave 16-row stripes
  const int tid = threadIdx.x, wv = tid >> 6, ln = tid & 63;
  const int bh = blockIdx.y, b = bh >> 4, h = bh & 15;
  const int q0 = blockIdx.x * 64;
  const bf16* qh  = qg  + (size_t)bh * (2048 * 64);
  const bf16* kh  = kg  + (size_t)bh * (2048 * 64);
  const bf16* vth = vtg + (size_t)bh * (64 * 2048);
  const int* mb = mask + b * 2048;
  const int g = ln >> 4, c = ln & 15;

  // hoist Q fragments (A-layout: row=c, k-chunk=g); 16 q-rows per wave
  bf16x8 qf[2];
#pragma unroll
  for (int ks = 0; ks < 2; ++ks)
    qf[ks] = *(const bf16x8*)(qh + (size_t)(q0 + wv * 16 + c) * 64 + ks * 32 + g * 8);

  // constant ones B-fragment: column 0 = 1 -> row-sum of P via MFMA
  bf16x8 onesf;
#pragma unroll
  for (int i = 0; i < 8; ++i) onesf[i] = (c == 0) ? (short)0x3F80 : (short)0;

  f32x4 o[4] = {};
  f32x4 ol = {};

  for (int kt = 0; kt < 32; ++kt) {
    // ---- scores = Q K^T (K frags direct from global; L2-resident) ----
    f32x4 sf[4] = {};
#pragma unroll
    for (int ks = 0; ks < 2; ++ks) {
      bf16x8 kf[4];
#pragma unroll
      for (int nk = 0; nk < 4; ++nk)
        kf[nk] = *(const bf16x8*)(kh + (size_t)(kt * 64 + nk * 16 + c) * 64 + ks * 32 + g * 8);
#pragma unroll
      for (int nk = 0; nk < 4; ++nk)
        sf[nk] = __builtin_amdgcn_mfma_f32_16x16x32_bf16(qf[ks], kf[nk], sf[nk], 0, 0, 0);
    }
    // ---- P = exp(min(s,30)), masked -> 0; bounce via wave-private swizzled LDS stripe ----
#pragma unroll
    for (int nk = 0; nk < 4; ++nk) {
      const bool live = (mb[kt * 64 + nk * 16 + c] != 0);
#pragma unroll
      for (int r = 0; r < 4; ++r) {
        const float p = live ? __expf(fminf(sf[nk][r], 30.0f)) : 0.0f;
        const int qr = wv * 16 + g * 4 + r;
        *(short*)((char*)Ps + qr * 128 + (((nk * 16 + c) * 2) ^ ((qr & 7) << 4))) = f2b(p);
      }
    }
    asm volatile("" ::: "memory");  // order P-writes before P-reads
    // ---- O += P V ; denominator accumulated as ones-column MFMA ----
#pragma unroll
    for (int ks = 0; ks < 2; ++ks) {
      const int qr = wv * 16 + c;
      const bf16x8 pf =
          *(const bf16x8*)((const char*)Ps + qr * 128 + ((ks * 64 + g * 16) ^ ((qr & 7) << 4)));
      bf16x8 vf[4];
#pragma unroll
      for (int nd = 0; nd < 4; ++nd)
        vf[nd] = *(const bf16x8*)(vth + (size_t)(nd * 16 + c) * 2048 + kt * 64 + ks * 32 + g * 8);
#pragma unroll
      for (int nd = 0; nd < 4; ++nd)
        o[nd] = __builtin_amdgcn_mfma_f32_16x16x32_bf16(pf, vf[nd], o[nd], 0, 0, 0);
      ol = __builtin_amdgcn_mfma_f32_16x16x32_bf16(pf, onesf, ol, 0, 0, 0);
    }
    asm volatile("" ::: "memory");  // order P-reads before next tile's P-writes
  }

  // normalize and store att[b*2048+q][h*64+d]
#pragma unroll
  for (int r = 0; r < 4; ++r) {
    const float lsum = __shfl(ol[r], ln & 48, 64);  // broadcast col-0 lane of the group
    const float inv = 1.0f / fmaxf(lsum, 1e-30f);
    const int qr = q0 + wv * 16 + g * 4 + r;
#pragma unroll
    for (int nd = 0; nd < 4; ++nd)
      att[(size_t)(b * 2048 + qr) * 1024 + h * 64 + nd * 16 + c] =
          __float2bfloat16(o[nd][r] * inv);
  }
}

extern "C" void kernel_launch(void* const* d_in, const int* in_sizes, int n_in,
                              void* d_out, int out_size, void* d_ws, size_t ws_size,
                              hipStream_t stream) {
  (void)in_sizes; (void)n_in; (void)out_size; (void)ws_size;
  const float* H    = (const float*)d_in[0];   // inputs are float32 per reference
  const int*   mask = (const int*)d_in[1];
  const float* Wq   = (const float*)d_in[2];
  const float* Wk   = (const float*)d_in[3];
  const float* Wv   = (const float*)d_in[4];
  const float* Wo   = (const float*)d_in[5];
  bf16* ws   = (bf16*)d_ws;
  bf16* wqT  = ws + OFF_WQT;
  bf16* wkT  = ws + OFF_WKT;
  bf16* wvT  = ws + OFF_WVT;
  bf16* woT  = ws + OFF_WOT;
  bf16* hb   = ws + OFF_HB;
  bf16* qws  = ws + OFF_Q;
  bf16* kws  = ws + OFF_K;
  bf16* vtws = ws + OFF_VT;
  bf16* attw = ws + OFF_ATT;

  transpose_w<<<dim3(16, 16, 4), 256, 0, stream>>>(Wq, Wk, Wv, Wo, ws);
  cvt_h<<<dim3(2048), 256, 0, stream>>>(H, hb);   // 4M elems, 8/thread
  // Q and K projections (z=0 -> Q scaled, z=1 -> K)
  gemm_k<0><<<dim3(8, 32, 2), 256, 0, stream>>>(hb, wqT, wkT, qws, kws);
  // V^T = WvT @ Hb^T  (M=1024 -> grid.y=8, N=4096 -> grid.x=32)
  gemm_k<1><<<dim3(32, 8, 1), 256, 0, stream>>>(wvT, hb, nullptr, vtws, nullptr);
  // attention: 64 q-rows per block, 1024 blocks
  attn_k<<<dim3(32, 32), 256, 0, stream>>>(qws, kws, vtws, mask, attw);
  // output projection -> float32 d_out
  gemm_k<2><<<dim3(8, 32, 1), 256, 0, stream>>>(attw, woT, nullptr, d_out, nullptr);
}

// Round 8
// 233.563 us; speedup vs baseline: 1.7914x; 1.7033x over previous
//
#include <hip/hip_runtime.h>
#include <hip/hip_bf16.h>
#include <cstdint>

using bf16 = __hip_bfloat16;
typedef __attribute__((ext_vector_type(8))) short bf16x8;
typedef __attribute__((ext_vector_type(4))) float f32x4;

// problem constants: DIM=1024, HEADS=16, HD=64, B=2, S=2048
// workspace layout (bf16 element offsets); total 24M elems = 48 MB
constexpr size_t OFF_WQT = 0;                 // 1M each, transposed bf16 weights
constexpr size_t OFF_WKT = (size_t)1 << 20;
constexpr size_t OFF_WVT = (size_t)2 << 20;
constexpr size_t OFF_WOT = (size_t)3 << 20;
constexpr size_t OFF_HB  = (size_t)4 << 20;  // H as bf16 [4096][1024]
constexpr size_t OFF_Q   = (size_t)8 << 20;  // [b*16+h][s][d]
constexpr size_t OFF_K   = (size_t)12 << 20; // [b*16+h][s][d]
constexpr size_t OFF_VT  = (size_t)16 << 20; // [b*16+h][d][s]
constexpr size_t OFF_ATT = (size_t)20 << 20; // [b*2048+s][h*64+d]

__device__ __forceinline__ void gload_lds16(const void* g, void* l) {
  auto gp = reinterpret_cast<const __attribute__((address_space(1))) void*>(
      reinterpret_cast<uintptr_t>(g));
  auto lp = reinterpret_cast<__attribute__((address_space(3))) void*>(
      static_cast<uint32_t>(reinterpret_cast<uintptr_t>(l)));
  __builtin_amdgcn_global_load_lds(gp, lp, 16, 0, 0);
}

__device__ __forceinline__ short f2b(float x) {
  return (short)__builtin_bit_cast(unsigned short, __float2bfloat16(x));
}

// ---------------- H: f32 -> bf16, 8 elems/thread ----------------
__global__ __launch_bounds__(256) void cvt_h(const float* __restrict__ in,
                                             bf16* __restrict__ out) {
  const int i = blockIdx.x * 256 + threadIdx.x;  // 4M/8 = 512K threads
  const f32x4 a = *(const f32x4*)(in + (size_t)i * 8);
  const f32x4 b = *(const f32x4*)(in + (size_t)i * 8 + 4);
  bf16x8 v;
  v[0] = f2b(a[0]); v[1] = f2b(a[1]); v[2] = f2b(a[2]); v[3] = f2b(a[3]);
  v[4] = f2b(b[0]); v[5] = f2b(b[1]); v[6] = f2b(b[2]); v[7] = f2b(b[3]);
  *(bf16x8*)((short*)out + (size_t)i * 8) = v;
}

// ---------------- weight transpose + cvt: WT[n][k] = bf16(W[k][n]) ----------------
__global__ __launch_bounds__(256) void transpose_w(
    const float* __restrict__ w0, const float* __restrict__ w1,
    const float* __restrict__ w2, const float* __restrict__ w3,
    bf16* __restrict__ ws) {
  __shared__ float t[64][65];
  const float* src = (blockIdx.z == 0) ? w0 : (blockIdx.z == 1) ? w1
                   : (blockIdx.z == 2) ? w2 : w3;
  bf16* dst = ws + ((size_t)blockIdx.z << 20);
  const int r0 = blockIdx.y * 64, c0 = blockIdx.x * 64;
  for (int i = threadIdx.x; i < 4096; i += 256) {
    const int r = i >> 6, c = i & 63;
    t[r][c] = src[(size_t)(r0 + r) * 1024 + c0 + c];
  }
  __syncthreads();
  for (int i = threadIdx.x; i < 4096; i += 256) {
    const int r = i >> 6, c = i & 63;
    dst[(size_t)(c0 + r) * 1024 + r0 + c] = __float2bfloat16(t[c][r]);
  }
}

// ---------------- GEMM: C = A(MxK) * Bt(NxK)^T, K=1024, tiles 128x128x64 ----------------
// MODE 0: A=Hb, Bt=WqT/WkT (z), C-> q/k ws [bh][s][d] (bf16), Q scaled by 0.125*log2e
// MODE 1: A=WvT (M=1024), Bt=Hb (N=4096), C-> vt ws [bh][d][s] (bf16)
// MODE 2: A=att, Bt=WoT, C-> d_out [m][n] (FLOAT32 - reference output dtype)
template <int MODE>
__global__ __launch_bounds__(256) void gemm_k(
    const bf16* __restrict__ A, const bf16* __restrict__ Bt0,
    const bf16* __restrict__ Bt1, void* __restrict__ C0, void* __restrict__ C1) {
  __shared__ __attribute__((aligned(16))) bf16 As[128 * 64];
  __shared__ __attribute__((aligned(16))) bf16 Bs[128 * 64];
  const int tid = threadIdx.x;
  const int wv = tid >> 6, ln = tid & 63;
  const int m0 = blockIdx.y * 128, n0 = blockIdx.x * 128;
  const bf16* Bt = (MODE == 0 && blockIdx.z == 1) ? Bt1 : Bt0;
  void* C = (MODE == 0 && blockIdx.z == 1) ? C1 : C0;
  const int wm = (wv >> 1) * 64, wn = (wv & 1) * 64;
  const int srow = ln >> 3, scol = (ln & 7) * 8;
  f32x4 acc[4][4] = {};

  for (int kt = 0; kt < 16; ++kt) {
    __syncthreads();  // previous tile fully consumed
    const int kb = kt * 64;
#pragma unroll
    for (int j = 0; j < 4; ++j) {
      const int rr = (wv * 4 + j) * 8 + srow;
      gload_lds16(A  + (size_t)(m0 + rr) * 1024 + kb + scol, As + (size_t)(wv * 4 + j) * 512);
      gload_lds16(Bt + (size_t)(n0 + rr) * 1024 + kb + scol, Bs + (size_t)(wv * 4 + j) * 512);
    }
    __syncthreads();  // compiler drains vmcnt(0) before barrier
#pragma unroll
    for (int ks = 0; ks < 2; ++ks) {
      bf16x8 af[4], bfr[4];
#pragma unroll
      for (int i = 0; i < 4; ++i) {
        af[i]  = *(const bf16x8*)(As + (wm + i * 16 + (ln & 15)) * 64 + ks * 32 + (ln >> 4) * 8);
        bfr[i] = *(const bf16x8*)(Bs + (wn + i * 16 + (ln & 15)) * 64 + ks * 32 + (ln >> 4) * 8);
      }
#pragma unroll
      for (int i = 0; i < 4; ++i)
#pragma unroll
        for (int j = 0; j < 4; ++j)
          acc[i][j] = __builtin_amdgcn_mfma_f32_16x16x32_bf16(af[i], bfr[j], acc[i][j], 0, 0, 0);
    }
  }

  // Q scale folds softmax 1/8 and log2(e) so attention can use exp2 directly
  const float scl = (MODE == 0 && blockIdx.z == 0) ? 0.125f * 1.44269504088896f : 1.0f;
#pragma unroll
  for (int i = 0; i < 4; ++i)
#pragma unroll
    for (int j = 0; j < 4; ++j)
#pragma unroll
      for (int r = 0; r < 4; ++r) {
        const int m = m0 + wm + i * 16 + (ln >> 4) * 4 + r;
        const int n = n0 + wn + j * 16 + (ln & 15);
        const float v = acc[i][j][r] * scl;
        if (MODE == 0) {
          // [b*16+h][s][d]: b=m>>11, s=m&2047, h=n>>6, d=n&63
          const size_t idx =
              ((size_t)((m >> 11) * 16 + (n >> 6)) << 17) + (size_t)(m & 2047) * 64 + (n & 63);
          ((bf16*)C)[idx] = __float2bfloat16(v);
        } else if (MODE == 1) {
          // C[m][n] = V^T value, m = h*64+d, n = b*2048+s -> vt[b][m][s]
          const size_t idx = ((size_t)(n >> 11) << 21) + (size_t)m * 2048 + (n & 2047);
          ((bf16*)C)[idx] = __float2bfloat16(v);
        } else {
          // final output: reference dtype is float32
          ((float*)C)[(size_t)m * 1024 + n] = v;
        }
      }
}

// ---------------- attention: per (b,h), 128 q-rows per block, 8 waves x 16 rows ----------------
// K/V tiles double-buffered in LDS, staged once per block (shared by 8 waves).
// LDS tiles use both-sides XOR swizzle: linear gload_lds dest + pre-swizzled global
// source + swizzled ds_read (byte ^= (row&7)<<4) -> conflict-free stride-128B reads.
__global__ __launch_bounds__(512) void attn_k(
    const bf16* __restrict__ qg, const bf16* __restrict__ kg,
    const bf16* __restrict__ vtg, const int* __restrict__ mask,
    bf16* __restrict__ att) {
  __shared__ __attribute__((aligned(16))) bf16 Ks[2][4096];  // [64 kv][64 d] swizzled
  __shared__ __attribute__((aligned(16))) bf16 Vs[2][4096];  // [64 d][64 kv] swizzled
  __shared__ __attribute__((aligned(16))) short Ps[128 * 64]; // per-wave 16-row stripes
  const int tid = threadIdx.x, wv = tid >> 6, ln = tid & 63;
  const int bh = blockIdx.y, b = bh >> 4, h = bh & 15;
  const int q0 = blockIdx.x * 128;
  const bf16* qh  = qg  + (size_t)bh * (2048 * 64);
  const bf16* kh  = kg  + (size_t)bh * (2048 * 64);
  const bf16* vth = vtg + (size_t)bh * (64 * 2048);
  const int* mb = mask + b * 2048;
  const int g = ln >> 4, c = ln & 15;
  // staging: thread t fills LDS byte t*16; row=t>>3, logical chunk=(t&7)^(row&7)
  const int srow = tid >> 3;
  const int slch = (tid & 7) ^ (srow & 7);
  const int xr = (c & 7) << 4;  // read-side XOR (row & 7)<<4, row = *16 + c

  // hoist Q fragments (A-layout: row=c, k-chunk=g); 16 q-rows per wave
  bf16x8 qf[2];
#pragma unroll
  for (int ks = 0; ks < 2; ++ks)
    qf[ks] = *(const bf16x8*)(qh + (size_t)(q0 + wv * 16 + c) * 64 + ks * 32 + g * 8);

  // constant ones B-fragment: column 0 = 1 -> row-sum of P via MFMA
  bf16x8 onesf;
#pragma unroll
  for (int i = 0; i < 8; ++i) onesf[i] = (c == 0) ? (short)0x3F80 : (short)0;

  f32x4 o[4] = {};
  f32x4 ol = {};

  // prologue: stage tile 0
  gload_lds16(kh + (size_t)srow * 64 + slch * 8, (char*)&Ks[0][0] + wv * 1024);
  gload_lds16(vth + (size_t)srow * 2048 + slch * 8, (char*)&Vs[0][0] + wv * 1024);
  __syncthreads();

  for (int kt = 0; kt < 32; ++kt) {
    const int cur = kt & 1;
    if (kt < 31) {  // prefetch next tile into the other buffer
      gload_lds16(kh + (size_t)((kt + 1) * 64 + srow) * 64 + slch * 8,
                  (char*)&Ks[cur ^ 1][0] + wv * 1024);
      gload_lds16(vth + (size_t)srow * 2048 + (kt + 1) * 64 + slch * 8,
                  (char*)&Vs[cur ^ 1][0] + wv * 1024);
    }
    // ---- scores = Q K^T from staged LDS ----
    f32x4 sf[4] = {};
#pragma unroll
    for (int ks = 0; ks < 2; ++ks) {
      bf16x8 kf[4];
#pragma unroll
      for (int nk = 0; nk < 4; ++nk)
        kf[nk] = *(const bf16x8*)((const char*)&Ks[cur][0] + (nk * 16 + c) * 128 +
                                  ((ks * 64 + g * 16) ^ xr));
#pragma unroll
      for (int nk = 0; nk < 4; ++nk)
        sf[nk] = __builtin_amdgcn_mfma_f32_16x16x32_bf16(qf[ks], kf[nk], sf[nk], 0, 0, 0);
    }
    // ---- P = exp2(min(s,43)) (log2e folded into Q scale), masked -> 0 ----
#pragma unroll
    for (int nk = 0; nk < 4; ++nk) {
      const bool live = (mb[kt * 64 + nk * 16 + c] != 0);
#pragma unroll
      for (int r = 0; r < 4; ++r) {
        const float p = live ? __builtin_amdgcn_exp2f(fminf(sf[nk][r], 43.0f)) : 0.0f;
        const int qr = wv * 16 + g * 4 + r;
        *(short*)((char*)Ps + qr * 128 + (((nk * 16 + c) * 2) ^ ((qr & 7) << 4))) = f2b(p);
      }
    }
    asm volatile("" ::: "memory");  // order P-writes before P-reads (wave-private stripe)
    // ---- O += P V ; denominator accumulated as ones-column MFMA ----
#pragma unroll
    for (int ks = 0; ks < 2; ++ks) {
      const int qr = wv * 16 + c;
      const bf16x8 pf =
          *(const bf16x8*)((const char*)Ps + qr * 128 + ((ks * 64 + g * 16) ^ ((qr & 7) << 4)));
      bf16x8 vf[4];
#pragma unroll
      for (int nd = 0; nd < 4; ++nd)
        vf[nd] = *(const bf16x8*)((const char*)&Vs[cur][0] + (nd * 16 + c) * 128 +
                                  ((ks * 64 + g * 16) ^ xr));
#pragma unroll
      for (int nd = 0; nd < 4; ++nd)
        o[nd] = __builtin_amdgcn_mfma_f32_16x16x32_bf16(pf, vf[nd], o[nd], 0, 0, 0);
      ol = __builtin_amdgcn_mfma_f32_16x16x32_bf16(pf, onesf, ol, 0, 0, 0);
    }
    asm volatile("" ::: "memory");  // order P-reads before next tile's P-writes
    __syncthreads();  // drains vmcnt(0): prefetch landed; all waves done with cur
  }

  // normalize and store att[b*2048+q][h*64+d]
#pragma unroll
  for (int r = 0; r < 4; ++r) {
    const float lsum = __shfl(ol[r], ln & 48, 64);  // broadcast col-0 lane of the group
    const float inv = 1.0f / fmaxf(lsum, 1e-30f);
    const int qr = q0 + wv * 16 + g * 4 + r;
#pragma unroll
    for (int nd = 0; nd < 4; ++nd)
      att[(size_t)(b * 2048 + qr) * 1024 + h * 64 + nd * 16 + c] =
          __float2bfloat16(o[nd][r] * inv);
  }
}

extern "C" void kernel_launch(void* const* d_in, const int* in_sizes, int n_in,
                              void* d_out, int out_size, void* d_ws, size_t ws_size,
                              hipStream_t stream) {
  (void)in_sizes; (void)n_in; (void)out_size; (void)ws_size;
  const float* H    = (const float*)d_in[0];   // inputs are float32 per reference
  const int*   mask = (const int*)d_in[1];
  const float* Wq   = (const float*)d_in[2];
  const float* Wk   = (const float*)d_in[3];
  const float* Wv   = (const float*)d_in[4];
  const float* Wo   = (const float*)d_in[5];
  bf16* ws   = (bf16*)d_ws;
  bf16* wqT  = ws + OFF_WQT;
  bf16* wkT  = ws + OFF_WKT;
  bf16* wvT  = ws + OFF_WVT;
  bf16* woT  = ws + OFF_WOT;
  bf16* hb   = ws + OFF_HB;
  bf16* qws  = ws + OFF_Q;
  bf16* kws  = ws + OFF_K;
  bf16* vtws = ws + OFF_VT;
  bf16* attw = ws + OFF_ATT;

  transpose_w<<<dim3(16, 16, 4), 256, 0, stream>>>(Wq, Wk, Wv, Wo, ws);
  cvt_h<<<dim3(2048), 256, 0, stream>>>(H, hb);   // 4M elems, 8/thread
  // Q and K projections (z=0 -> Q scaled, z=1 -> K)
  gemm_k<0><<<dim3(8, 32, 2), 256, 0, stream>>>(hb, wqT, wkT, qws, kws);
  // V^T = WvT @ Hb^T  (M=1024 -> grid.y=8, N=4096 -> grid.x=32)
  gemm_k<1><<<dim3(32, 8, 1), 256, 0, stream>>>(wvT, hb, nullptr, vtws, nullptr);
  // attention: 128 q-rows per block, 8 waves, LDS-staged K/V
  attn_k<<<dim3(16, 32), 512, 0, stream>>>(qws, kws, vtws, mask, attw);
  // output projection -> float32 d_out
  gemm_k<2><<<dim3(8, 32, 1), 256, 0, stream>>>(attw, woT, nullptr, d_out, nullptr);
}